// Round 1
// baseline (1074.255 us; speedup 1.0000x reference)
//
#include <hip/hip_runtime.h>
#include <hip/hip_bf16.h>
#include <cstdint>
#include <cstddef>

#define N_S 4096
#define N_Kn 8192
#define HID 1024
#define SENT 1024
#define K3 3072

typedef __attribute__((ext_vector_type(4))) float f4;
typedef __attribute__((ext_vector_type(8))) short bf8;

__device__ inline unsigned short f2bf(float x) {
    union { float f; unsigned int u; } v; v.f = x;
    unsigned int r = v.u + 0x7fffu + ((v.u >> 16) & 1u);   // RNE
    return (unsigned short)(r >> 16);
}
__device__ inline float bf2f(unsigned short u) {
    union { unsigned int u; float f; } v; v.u = ((unsigned int)u) << 16;
    return v.f;
}

// ---------------------------------------------------------------------------
// Tiled transpose: in[R][C] -> out[C][R].  grid = (C/32, R/32), block = 256.
// ---------------------------------------------------------------------------
__global__ __launch_bounds__(256) void transpose_f32(
    const float* __restrict__ in, float* __restrict__ out, int R, int C)
{
    __shared__ float tile[32][33];
    const int bx = blockIdx.x * 32, by = blockIdx.y * 32;
    const int tx = threadIdx.x & 31, ty = threadIdx.x >> 5;  // ty: 0..7
#pragma unroll
    for (int i = 0; i < 32; i += 8)
        tile[ty + i][tx] = in[(size_t)(by + ty + i) * C + bx + tx];
    __syncthreads();
#pragma unroll
    for (int i = 0; i < 32; i += 8)
        out[(size_t)(bx + ty + i) * R + by + tx] = tile[tx][ty + i];
}

__global__ __launch_bounds__(256) void transpose_f32_bf16(
    const float* __restrict__ in, unsigned short* __restrict__ out, int R, int C)
{
    __shared__ float tile[32][33];
    const int bx = blockIdx.x * 32, by = blockIdx.y * 32;
    const int tx = threadIdx.x & 31, ty = threadIdx.x >> 5;
#pragma unroll
    for (int i = 0; i < 32; i += 8)
        tile[ty + i][tx] = in[(size_t)(by + ty + i) * C + bx + tx];
    __syncthreads();
#pragma unroll
    for (int i = 0; i < 32; i += 8)
        out[(size_t)(bx + ty + i) * R + by + tx] = f2bf(tile[tx][ty + i]);
}

// ---------------------------------------------------------------------------
// GEMM: C[M][N] = A[M][K] @ B^T  (B given as [N][K] row-major) + bias
// MODE 0: A,B f32 sources, split-bf16 (hi*hi + hi*lo + lo*hi) -> ~fp32 acc
// MODE 1: A f32 source (hi only), B bf16 source, plain bf16
// tile 128x128, BK=32, 4 waves (2x2 of 64x64), mfma_f32_16x16x32_bf16
// ---------------------------------------------------------------------------
template <int MODE>
__global__ __launch_bounds__(256) void gemm_kernel(
    const void* __restrict__ Aptr, const void* __restrict__ Bptr,
    float* __restrict__ C, const float* __restrict__ bias,
    int M, int N, int Kd)
{
    constexpr int LS = 40;  // padded lds stride (elements): breaks bank conflicts
    __shared__ unsigned short sA_hi[128 * LS];
    __shared__ unsigned short sB_hi[128 * LS];
    __shared__ unsigned short sA_lo[MODE == 0 ? 128 * LS : 8];
    __shared__ unsigned short sB_lo[MODE == 0 ? 128 * LS : 8];

    const int t = threadIdx.x;
    const int srow = t >> 1;             // 0..127 : staging row
    const int scol = (t & 1) << 4;       // 0 or 16 : staging col base
    const long brow = (long)blockIdx.y * 128;
    const long bcol = (long)blockIdx.x * 128;

    const int lane = t & 63;
    const int wr = ((t >> 6) >> 1) * 64;  // wave row offset (2x2 waves)
    const int wc = ((t >> 6) & 1) * 64;   // wave col offset
    const int fr = lane & 15;             // fragment row (A) / col (B)
    const int kg = lane >> 4;             // k-group 0..3 (8 bf16 each)

    f4 acc[4][4];
#pragma unroll
    for (int m = 0; m < 4; m++)
#pragma unroll
        for (int n = 0; n < 4; n++) acc[m][n] = (f4){0.f, 0.f, 0.f, 0.f};

    const int nkt = Kd >> 5;
    for (int kt = 0; kt < nkt; ++kt) {
        const long koff = (long)kt * 32 + scol;
        const int lo = srow * LS + scol;
        if (MODE == 0) {
            const float* pA = (const float*)Aptr + (brow + srow) * (long)Kd + koff;
            const float* pB = (const float*)Bptr + (bcol + srow) * (long)Kd + koff;
            float av[16], bv[16];
#pragma unroll
            for (int i = 0; i < 16; i += 4) {
                *(f4*)&av[i] = *(const f4*)(pA + i);
                *(f4*)&bv[i] = *(const f4*)(pB + i);
            }
            unsigned short ah[16], al[16], bh[16], bl[16];
#pragma unroll
            for (int i = 0; i < 16; i++) {
                ah[i] = f2bf(av[i]); al[i] = f2bf(av[i] - bf2f(ah[i]));
                bh[i] = f2bf(bv[i]); bl[i] = f2bf(bv[i] - bf2f(bh[i]));
            }
            *(bf8*)&sA_hi[lo] = *(bf8*)&ah[0]; *(bf8*)&sA_hi[lo + 8] = *(bf8*)&ah[8];
            *(bf8*)&sA_lo[lo] = *(bf8*)&al[0]; *(bf8*)&sA_lo[lo + 8] = *(bf8*)&al[8];
            *(bf8*)&sB_hi[lo] = *(bf8*)&bh[0]; *(bf8*)&sB_hi[lo + 8] = *(bf8*)&bh[8];
            *(bf8*)&sB_lo[lo] = *(bf8*)&bl[0]; *(bf8*)&sB_lo[lo + 8] = *(bf8*)&bl[8];
        } else {
            const float* pA = (const float*)Aptr + (brow + srow) * (long)Kd + koff;
            const unsigned short* pB = (const unsigned short*)Bptr + (bcol + srow) * (long)Kd + koff;
            float av[16];
#pragma unroll
            for (int i = 0; i < 16; i += 4) *(f4*)&av[i] = *(const f4*)(pA + i);
            unsigned short ah[16];
#pragma unroll
            for (int i = 0; i < 16; i++) ah[i] = f2bf(av[i]);
            *(bf8*)&sA_hi[lo] = *(bf8*)&ah[0]; *(bf8*)&sA_hi[lo + 8] = *(bf8*)&ah[8];
            *(bf8*)&sB_hi[lo] = *(const bf8*)pB;
            *(bf8*)&sB_hi[lo + 8] = *(const bf8*)(pB + 8);
        }
        __syncthreads();

        bf8 fah[4], fbh[4], fal[4], fbl[4];
#pragma unroll
        for (int m = 0; m < 4; m++) {
            fah[m] = *(bf8*)&sA_hi[(wr + m * 16 + fr) * LS + kg * 8];
            fbh[m] = *(bf8*)&sB_hi[(wc + m * 16 + fr) * LS + kg * 8];
            if (MODE == 0) {
                fal[m] = *(bf8*)&sA_lo[(wr + m * 16 + fr) * LS + kg * 8];
                fbl[m] = *(bf8*)&sB_lo[(wc + m * 16 + fr) * LS + kg * 8];
            }
        }
#pragma unroll
        for (int m = 0; m < 4; m++) {
#pragma unroll
            for (int n = 0; n < 4; n++) {
                acc[m][n] = __builtin_amdgcn_mfma_f32_16x16x32_bf16(fah[m], fbh[n], acc[m][n], 0, 0, 0);
                if (MODE == 0) {
                    acc[m][n] = __builtin_amdgcn_mfma_f32_16x16x32_bf16(fah[m], fbl[n], acc[m][n], 0, 0, 0);
                    acc[m][n] = __builtin_amdgcn_mfma_f32_16x16x32_bf16(fal[m], fbh[n], acc[m][n], 0, 0, 0);
                }
            }
        }
        __syncthreads();
    }

    // epilogue: C/D frag layout col = lane&15, row = (lane>>4)*4 + reg
#pragma unroll
    for (int n = 0; n < 4; n++) {
        const long c = bcol + wc + n * 16 + fr;
        const float bv = bias ? bias[c] : 0.f;
#pragma unroll
        for (int m = 0; m < 4; m++) {
            const long r0 = brow + wr + m * 16 + kg * 4;
#pragma unroll
            for (int r = 0; r < 4; r++)
                C[(r0 + r) * (long)N + c] = acc[m][n][r] + bv;
        }
    }
}

// ---------------------------------------------------------------------------
// Column softmax over align [N_S rows][N_Kn cols] (softmax along rows, axis 0)
// ---------------------------------------------------------------------------
#define RCHUNK 128  // 4096 / 32 row chunks

__global__ __launch_bounds__(256) void softmax_partial(
    const float* __restrict__ align, float* __restrict__ pm, float* __restrict__ ps)
{
    const int col = blockIdx.x * 256 + threadIdx.x;
    const int r0 = blockIdx.y * RCHUNK;
    float m = -3.4e38f;
    for (int r = 0; r < RCHUNK; r++)
        m = fmaxf(m, align[(size_t)(r0 + r) * N_Kn + col]);
    float s = 0.f;
    for (int r = 0; r < RCHUNK; r++)
        s += __expf(align[(size_t)(r0 + r) * N_Kn + col] - m);
    pm[(size_t)blockIdx.y * N_Kn + col] = m;
    ps[(size_t)blockIdx.y * N_Kn + col] = s;
}

__global__ __launch_bounds__(256) void softmax_combine(
    const float* __restrict__ pm, const float* __restrict__ ps,
    float* __restrict__ fm, float* __restrict__ fsinv)
{
    const int col = blockIdx.x * 256 + threadIdx.x;
    float m = -3.4e38f;
#pragma unroll
    for (int i = 0; i < 32; i++) m = fmaxf(m, pm[(size_t)i * N_Kn + col]);
    float s = 0.f;
#pragma unroll
    for (int i = 0; i < 32; i++)
        s += ps[(size_t)i * N_Kn + col] * __expf(pm[(size_t)i * N_Kn + col] - m);
    fm[col] = m;
    fsinv[col] = 1.f / s;
}

__global__ __launch_bounds__(256) void softmax_norm(
    float* __restrict__ align, const float* __restrict__ fm, const float* __restrict__ fsinv)
{
    const int col = blockIdx.x * 256 + threadIdx.x;
    const int r0 = blockIdx.y * RCHUNK;
    const float m = fm[col], si = fsinv[col];
    for (int r = 0; r < RCHUNK; r++) {
        const size_t idx = (size_t)(r0 + r) * N_Kn + col;
        align[idx] = __expf(align[idx] - m) * si;
    }
}

// ---------------------------------------------------------------------------
extern "C" void kernel_launch(void* const* d_in, const int* in_sizes, int n_in,
                              void* d_out, int out_size, void* d_ws, size_t ws_size,
                              hipStream_t stream)
{
    const float* sentences = (const float*)d_in[0];  // [4096][1024]
    const float* knowledge = (const float*)d_in[1];  // [8192][3072]
    const float* Ws = (const float*)d_in[2];         // [1024][1024] (in,out)
    const float* bs = (const float*)d_in[3];         // [1024]
    const float* Wk = (const float*)d_in[4];         // [3072][1024]
    const float* bk = (const float*)d_in[5];         // [1024]

    float* out_fused = (float*)d_out;                           // [4096][3072]
    float* out_attn = (float*)d_out + (size_t)N_S * K3;         // [4096][8192] (also holds align pre-softmax)

    // workspace layout (~113 MB)
    char* w = (char*)d_ws;
    float* WsT = (float*)w;  w += (size_t)SENT * HID * 4;        // [1024][1024]
    float* WkT = (float*)w;  w += (size_t)HID * K3 * 4;          // [1024][3072]
    float* Smat = (float*)w; w += (size_t)N_S * HID * 4;         // [4096][1024]
    float* Kmat = (float*)w; w += (size_t)N_Kn * HID * 4;        // [8192][1024]
    unsigned short* kT = (unsigned short*)w; w += (size_t)K3 * N_Kn * 2;  // [3072][8192] bf16
    float* pm = (float*)w;   w += (size_t)32 * N_Kn * 4;
    float* ps = (float*)w;   w += (size_t)32 * N_Kn * 4;
    float* fm = (float*)w;   w += (size_t)N_Kn * 4;
    float* fsv = (float*)w;  w += (size_t)N_Kn * 4;

    // 1. transposes: weights to [N][K] (B^T) form; knowledge^T to bf16 for GEMM4
    transpose_f32<<<dim3(HID / 32, SENT / 32), 256, 0, stream>>>(Ws, WsT, SENT, HID);
    transpose_f32<<<dim3(HID / 32, K3 / 32), 256, 0, stream>>>(Wk, WkT, K3, HID);
    transpose_f32_bf16<<<dim3(K3 / 32, N_Kn / 32), 256, 0, stream>>>(knowledge, kT, N_Kn, K3);

    // 2. S = sentences @ Ws + bs   [4096][1024]  (split-bf16 ~ fp32 accuracy)
    gemm_kernel<0><<<dim3(HID / 128, N_S / 128), 256, 0, stream>>>(
        sentences, WsT, Smat, bs, N_S, HID, SENT);

    // 3. K = knowledge @ Wk + bk   [8192][1024]
    gemm_kernel<0><<<dim3(HID / 128, N_Kn / 128), 256, 0, stream>>>(
        knowledge, WkT, Kmat, bk, N_Kn, HID, K3);

    // 4. align = S @ K^T           [4096][8192] -> written into attentions slot
    gemm_kernel<0><<<dim3(N_Kn / 128, N_S / 128), 256, 0, stream>>>(
        Smat, Kmat, out_attn, nullptr, N_S, N_Kn, HID);

    // 5. column softmax (axis 0), in place
    softmax_partial<<<dim3(N_Kn / 256, N_S / RCHUNK), 256, 0, stream>>>(out_attn, pm, ps);
    softmax_combine<<<dim3(N_Kn / 256), 256, 0, stream>>>(pm, ps, fm, fsv);
    softmax_norm<<<dim3(N_Kn / 256, N_S / RCHUNK), 256, 0, stream>>>(out_attn, fm, fsv);

    // 6. fused = attn @ knowledge  [4096][3072]  (plain bf16: attn f32->hi, kT bf16)
    gemm_kernel<1><<<dim3(K3 / 128, N_S / 128), 256, 0, stream>>>(
        out_attn, kT, out_fused, nullptr, N_S, K3, N_Kn);
}

// Round 2
// 909.259 us; speedup vs baseline: 1.1815x; 1.1815x over previous
//
#include <hip/hip_runtime.h>
#include <hip/hip_bf16.h>
#include <cstdint>
#include <cstddef>

#define N_S 4096
#define N_Kn 8192
#define HID 1024
#define SENT 1024
#define K3 3072

typedef __attribute__((ext_vector_type(4))) float f4;
typedef __attribute__((ext_vector_type(8))) short bf8;
typedef __attribute__((ext_vector_type(4))) short bf4;
typedef unsigned short u16;

__device__ __forceinline__ u16 f2bf(float x) {
    union { float f; unsigned int u; } v; v.f = x;
    unsigned int r = v.u + 0x7fffu + ((v.u >> 16) & 1u);   // RNE
    return (u16)(r >> 16);
}
__device__ __forceinline__ float bf2f(u16 u) {
    union { unsigned int u; float f; } v; v.u = ((unsigned int)u) << 16;
    return v.f;
}

// async global->LDS, 16 bytes per lane; LDS dest = wave-uniform base + lane*16
__device__ __forceinline__ void gl16(const u16* g, u16* l) {
    __builtin_amdgcn_global_load_lds(
        (const __attribute__((address_space(1))) void*)g,
        (__attribute__((address_space(3))) void*)l, 16, 0, 0);
}

// ---------------------------------------------------------------------------
// Transposes
// ---------------------------------------------------------------------------
__global__ __launch_bounds__(256) void transpose_split_f32(
    const float* __restrict__ in, u16* __restrict__ hi, u16* __restrict__ lo,
    int R, int C)
{
    __shared__ float tile[32][33];
    const int bx = blockIdx.x * 32, by = blockIdx.y * 32;
    const int tx = threadIdx.x & 31, ty = threadIdx.x >> 5;
#pragma unroll
    for (int i = 0; i < 32; i += 8)
        tile[ty + i][tx] = in[(size_t)(by + ty + i) * C + bx + tx];
    __syncthreads();
#pragma unroll
    for (int i = 0; i < 32; i += 8) {
        const float v = tile[tx][ty + i];
        const u16 h = f2bf(v);
        const size_t o = (size_t)(bx + ty + i) * R + by + tx;
        hi[o] = h;
        lo[o] = f2bf(v - bf2f(h));
    }
}

__global__ __launch_bounds__(256) void transpose_f32_bf16(
    const float* __restrict__ in, u16* __restrict__ out, int R, int C)
{
    __shared__ float tile[32][33];
    const int bx = blockIdx.x * 32, by = blockIdx.y * 32;
    const int tx = threadIdx.x & 31, ty = threadIdx.x >> 5;
#pragma unroll
    for (int i = 0; i < 32; i += 8)
        tile[ty + i][tx] = in[(size_t)(by + ty + i) * C + bx + tx];
    __syncthreads();
#pragma unroll
    for (int i = 0; i < 32; i += 8)
        out[(size_t)(bx + ty + i) * R + by + tx] = f2bf(tile[tx][ty + i]);
}

// ---------------------------------------------------------------------------
// GEMM: C[M][N] = A[M][K] @ B^T (B stored [N][K]) (+ bias)
// SPLIT: 3-product split-bf16 (ah*bh + ah*bl + al*bh) ~ fp32 accuracy
// AF32:  A is f32, converted (and split) on the fly in registers
//        otherwise A is pre-split bf16 and staged via global_load_lds
// EPIS:  epilogue writes (acc+bias) as split hi/lo bf16; else f32 store
// tile 128x128, BK=32, 4 waves (2x2 of 64x64), mfma_f32_16x16x32_bf16
// ---------------------------------------------------------------------------
template <bool SPLIT, bool AF32, bool EPIS>
__global__ __launch_bounds__(256) void gemm_mfma(
    const void* __restrict__ Aany, const u16* __restrict__ Alo_,
    const u16* __restrict__ Bhi_, const u16* __restrict__ Blo_,
    float* __restrict__ Cf, u16* __restrict__ Chi, u16* __restrict__ Clo,
    const float* __restrict__ bias, int N, int Kd)
{
    constexpr int SA = AF32 ? 48 : 32;   // padded stride only when reg-staged
    __shared__ u16 sAh[128 * SA];
    __shared__ u16 sAl[SPLIT ? 128 * SA : 8];
    __shared__ u16 sBh[128 * 32];
    __shared__ u16 sBl[SPLIT ? 128 * 32 : 8];

    const int t = threadIdx.x;
    const int w = t >> 6;            // wave id 0..3
    const int l = t & 63;            // lane
    const long brow = (long)blockIdx.y * 128;
    const long bcol = (long)blockIdx.x * 128;

    // gload geometry: lane l covers row (i*64 + w*16 + l/4), col8 (l%4)*8
    const int grow = l >> 2;
    const int gcol = (l & 3) * 8;

    // fragment geometry
    const int wr = (w >> 1) * 64;
    const int wc = (w & 1) * 64;
    const int fr = l & 15;
    const int kg = l >> 4;

    f4 acc[4][4];
#pragma unroll
    for (int m = 0; m < 4; m++)
#pragma unroll
        for (int n = 0; n < 4; n++) acc[m][n] = (f4){0.f, 0.f, 0.f, 0.f};

    const int nkt = Kd >> 5;
    for (int kt = 0; kt < nkt; ++kt) {
        const int k0 = kt * 32;

        // ---- stage B (always pre-split bf16, async direct-to-LDS) ----
#pragma unroll
        for (int i = 0; i < 2; ++i) {
            const long r = bcol + i * 64 + w * 16 + grow;
            const int lb = i * 2048 + w * 512;     // wave-uniform LDS base (elems)
            gl16(Bhi_ + r * Kd + k0 + gcol, sBh + lb);
            if constexpr (SPLIT) gl16(Blo_ + r * Kd + k0 + gcol, sBl + lb);
        }

        // ---- stage A ----
        if constexpr (!AF32) {
            const u16* Ahi = (const u16*)Aany;
#pragma unroll
            for (int i = 0; i < 2; ++i) {
                const long r = brow + i * 64 + w * 16 + grow;
                const int lb = i * 2048 + w * 512;
                gl16(Ahi + r * Kd + k0 + gcol, sAh + lb);
                if constexpr (SPLIT) gl16(Alo_ + r * Kd + k0 + gcol, sAl + lb);
            }
        } else {
            // coalesced f32: 8 lanes x 16B per row, 8 rows per wave per issue
            const float* Af = (const float*)Aany;
            const int ar = w * 8 + (l >> 3);
            const int cF = (l & 7) * 4;
#pragma unroll
            for (int j = 0; j < 4; ++j) {
                const int r = j * 32 + ar;
                const f4 v = *(const f4*)(Af + (brow + r) * (long)Kd + k0 + cF);
                u16 h[4], lw[4];
#pragma unroll
                for (int q = 0; q < 4; ++q) {
                    h[q] = f2bf(v[q]);
                    if constexpr (SPLIT) lw[q] = f2bf(v[q] - bf2f(h[q]));
                }
                *(bf4*)&sAh[r * SA + cF] = *(bf4*)h;
                if constexpr (SPLIT) *(bf4*)&sAl[r * SA + cF] = *(bf4*)lw;
            }
        }
        __syncthreads();

        // ---- fragments + MFMA ----
        bf8 fah[4], fbh[4], fal[4], fbl[4];
#pragma unroll
        for (int m = 0; m < 4; ++m) {
            fah[m] = *(bf8*)&sAh[(wr + m * 16 + fr) * SA + kg * 8];
            fbh[m] = *(bf8*)&sBh[(wc + m * 16 + fr) * 32 + kg * 8];
            if constexpr (SPLIT) {
                fal[m] = *(bf8*)&sAl[(wr + m * 16 + fr) * SA + kg * 8];
                fbl[m] = *(bf8*)&sBl[(wc + m * 16 + fr) * 32 + kg * 8];
            }
        }
#pragma unroll
        for (int m = 0; m < 4; ++m)
#pragma unroll
            for (int n = 0; n < 4; ++n) {
                acc[m][n] = __builtin_amdgcn_mfma_f32_16x16x32_bf16(fah[m], fbh[n], acc[m][n], 0, 0, 0);
                if constexpr (SPLIT) {
                    acc[m][n] = __builtin_amdgcn_mfma_f32_16x16x32_bf16(fah[m], fbl[n], acc[m][n], 0, 0, 0);
                    acc[m][n] = __builtin_amdgcn_mfma_f32_16x16x32_bf16(fal[m], fbh[n], acc[m][n], 0, 0, 0);
                }
            }
        __syncthreads();
    }

    // ---- epilogue: C/D layout col = lane&15, row = (lane>>4)*4 + reg ----
#pragma unroll
    for (int n = 0; n < 4; ++n) {
        const long c = bcol + wc + n * 16 + fr;
        float bv = 0.f;
        if constexpr (EPIS) bv = bias[c];
#pragma unroll
        for (int m = 0; m < 4; ++m) {
            const long r0 = brow + wr + m * 16 + kg * 4;
#pragma unroll
            for (int r = 0; r < 4; ++r) {
                const float v = acc[m][n][r] + bv;
                if constexpr (EPIS) {
                    const u16 h = f2bf(v);
                    Chi[(r0 + r) * (long)N + c] = h;
                    Clo[(r0 + r) * (long)N + c] = f2bf(v - bf2f(h));
                } else {
                    Cf[(r0 + r) * (long)N + c] = v;
                }
            }
        }
    }
}

// ---------------------------------------------------------------------------
// Column softmax over align [N_S rows][N_Kn cols] (softmax along axis 0)
// ---------------------------------------------------------------------------
#define RCHUNK 128

__global__ __launch_bounds__(256) void softmax_partial(
    const float* __restrict__ align, float* __restrict__ pm, float* __restrict__ ps)
{
    const int col = blockIdx.x * 256 + threadIdx.x;
    const int r0 = blockIdx.y * RCHUNK;
    float m = -3.4e38f;
    for (int r = 0; r < RCHUNK; r++)
        m = fmaxf(m, align[(size_t)(r0 + r) * N_Kn + col]);
    float s = 0.f;
    for (int r = 0; r < RCHUNK; r++)
        s += __expf(align[(size_t)(r0 + r) * N_Kn + col] - m);
    pm[(size_t)blockIdx.y * N_Kn + col] = m;
    ps[(size_t)blockIdx.y * N_Kn + col] = s;
}

__global__ __launch_bounds__(256) void softmax_combine(
    const float* __restrict__ pm, const float* __restrict__ ps,
    float* __restrict__ fm, float* __restrict__ fsinv)
{
    const int col = blockIdx.x * 256 + threadIdx.x;
    float m = -3.4e38f;
#pragma unroll
    for (int i = 0; i < 32; i++) m = fmaxf(m, pm[(size_t)i * N_Kn + col]);
    float s = 0.f;
#pragma unroll
    for (int i = 0; i < 32; i++)
        s += ps[(size_t)i * N_Kn + col] * __expf(pm[(size_t)i * N_Kn + col] - m);
    fm[col] = m;
    fsinv[col] = 1.f / s;
}

__global__ __launch_bounds__(256) void softmax_norm(
    float* __restrict__ align, const float* __restrict__ fm, const float* __restrict__ fsinv)
{
    const int col = blockIdx.x * 256 + threadIdx.x;
    const int r0 = blockIdx.y * RCHUNK;
    const float m = fm[col], si = fsinv[col];
    for (int r = 0; r < RCHUNK; r++) {
        const size_t idx = (size_t)(r0 + r) * N_Kn + col;
        align[idx] = __expf(align[idx] - m) * si;
    }
}

// ---------------------------------------------------------------------------
extern "C" void kernel_launch(void* const* d_in, const int* in_sizes, int n_in,
                              void* d_out, int out_size, void* d_ws, size_t ws_size,
                              hipStream_t stream)
{
    const float* sentences = (const float*)d_in[0];  // [4096][1024]
    const float* knowledge = (const float*)d_in[1];  // [8192][3072]
    const float* Ws = (const float*)d_in[2];         // [1024][1024] (in,out)
    const float* bs = (const float*)d_in[3];         // [1024]
    const float* Wk = (const float*)d_in[4];         // [3072][1024]
    const float* bk = (const float*)d_in[5];         // [1024]

    float* out_fused = (float*)d_out;                        // [4096][3072]
    float* out_attn = (float*)d_out + (size_t)N_S * K3;      // [4096][8192]

    // workspace (~119 MB, same footprint as the passing round-1 layout)
    char* w = (char*)d_ws;
    u16* WsT_hi = (u16*)w; w += (size_t)HID * SENT * 2;      // [1024][1024]
    u16* WsT_lo = (u16*)w; w += (size_t)HID * SENT * 2;
    u16* WkT_hi = (u16*)w; w += (size_t)HID * K3 * 2;        // [1024][3072]
    u16* WkT_lo = (u16*)w; w += (size_t)HID * K3 * 2;
    u16* S_hi   = (u16*)w; w += (size_t)N_S * HID * 2;       // [4096][1024]
    u16* S_lo   = (u16*)w; w += (size_t)N_S * HID * 2;
    u16* K_hi   = (u16*)w; w += (size_t)N_Kn * HID * 2;      // [8192][1024]
    u16* K_lo   = (u16*)w; w += (size_t)N_Kn * HID * 2;
    u16* kT     = (u16*)w; w += (size_t)K3 * N_Kn * 2;       // [3072][8192]
    float* pm   = (float*)w; w += (size_t)32 * N_Kn * 4;
    float* ps   = (float*)w; w += (size_t)32 * N_Kn * 4;
    float* fm   = (float*)w; w += (size_t)N_Kn * 4;
    float* fsv  = (float*)w; w += (size_t)N_Kn * 4;

    // 1. weight transposes (split) + knowledge^T (bf16, hi only)
    transpose_split_f32<<<dim3(HID / 32, SENT / 32), 256, 0, stream>>>(Ws, WsT_hi, WsT_lo, SENT, HID);
    transpose_split_f32<<<dim3(HID / 32, K3 / 32), 256, 0, stream>>>(Wk, WkT_hi, WkT_lo, K3, HID);
    transpose_f32_bf16<<<dim3(K3 / 32, N_Kn / 32), 256, 0, stream>>>(knowledge, kT, N_Kn, K3);

    // 2. S = sentences @ Ws + bs -> split bf16 [4096][1024]
    gemm_mfma<true, true, true><<<dim3(HID / 128, N_S / 128), 256, 0, stream>>>(
        sentences, nullptr, WsT_hi, WsT_lo, nullptr, S_hi, S_lo, bs, HID, SENT);

    // 3. K = knowledge @ Wk + bk -> split bf16 [8192][1024]
    gemm_mfma<true, true, true><<<dim3(HID / 128, N_Kn / 128), 256, 0, stream>>>(
        knowledge, nullptr, WkT_hi, WkT_lo, nullptr, K_hi, K_lo, bk, HID, K3);

    // 4. align = S @ K^T -> f32 into attentions slot (fully gload-staged)
    gemm_mfma<true, false, false><<<dim3(N_Kn / 128, N_S / 128), 256, 0, stream>>>(
        S_hi, S_lo, K_hi, K_lo, out_attn, nullptr, nullptr, nullptr, N_Kn, HID);

    // 5. column softmax (axis 0), in place
    softmax_partial<<<dim3(N_Kn / 256, N_S / RCHUNK), 256, 0, stream>>>(out_attn, pm, ps);
    softmax_combine<<<dim3(N_Kn / 256), 256, 0, stream>>>(pm, ps, fm, fsv);
    softmax_norm<<<dim3(N_Kn / 256, N_S / RCHUNK), 256, 0, stream>>>(out_attn, fm, fsv);

    // 6. fused = attn @ knowledge -> f32 (attn f32 reg-staged, kT bf16 gload)
    gemm_mfma<false, true, false><<<dim3(K3 / 128, N_S / 128), 256, 0, stream>>>(
        out_attn, nullptr, kT, nullptr, out_fused, nullptr, nullptr, nullptr, K3, N_Kn);
}

// Round 3
// 848.058 us; speedup vs baseline: 1.2667x; 1.0722x over previous
//
#include <hip/hip_runtime.h>
#include <hip/hip_bf16.h>
#include <cstdint>
#include <cstddef>

#define N_S 4096
#define N_Kn 8192
#define HID 1024
#define SENT 1024
#define K3 3072

typedef __attribute__((ext_vector_type(4))) float f4;
typedef __attribute__((ext_vector_type(8))) short bf8;
typedef __attribute__((ext_vector_type(4))) short bf4;
typedef unsigned short u16;

__device__ __forceinline__ u16 f2bf(float x) {
    __hip_bfloat16 h = __float2bfloat16(x);   // HW RNE (v_cvt_pk_bf16_f32)
    return __builtin_bit_cast(u16, h);
}
__device__ __forceinline__ float bf2f(u16 u) {
    union { unsigned int u; float f; } v; v.u = ((unsigned int)u) << 16;
    return v.f;
}

// async global->LDS, 16 bytes per lane; LDS dest = wave-uniform base + lane*16
__device__ __forceinline__ void gl16(const u16* g, u16* l) {
    __builtin_amdgcn_global_load_lds(
        (const __attribute__((address_space(1))) void*)g,
        (__attribute__((address_space(3))) void*)l, 16, 0, 0);
}

// ---------------------------------------------------------------------------
// Transposes
// ---------------------------------------------------------------------------
__global__ __launch_bounds__(256) void transpose_split_f32(
    const float* __restrict__ in, u16* __restrict__ hi, u16* __restrict__ lo,
    int R, int C)
{
    __shared__ float tile[32][33];
    const int bx = blockIdx.x * 32, by = blockIdx.y * 32;
    const int tx = threadIdx.x & 31, ty = threadIdx.x >> 5;
#pragma unroll
    for (int i = 0; i < 32; i += 8)
        tile[ty + i][tx] = in[(size_t)(by + ty + i) * C + bx + tx];
    __syncthreads();
#pragma unroll
    for (int i = 0; i < 32; i += 8) {
        const float v = tile[tx][ty + i];
        const u16 h = f2bf(v);
        const size_t o = (size_t)(bx + ty + i) * R + by + tx;
        hi[o] = h;
        lo[o] = f2bf(v - bf2f(h));
    }
}

__global__ __launch_bounds__(256) void transpose_f32_bf16(
    const float* __restrict__ in, u16* __restrict__ out, int R, int C)
{
    __shared__ float tile[32][33];
    const int bx = blockIdx.x * 32, by = blockIdx.y * 32;
    const int tx = threadIdx.x & 31, ty = threadIdx.x >> 5;
#pragma unroll
    for (int i = 0; i < 32; i += 8)
        tile[ty + i][tx] = in[(size_t)(by + ty + i) * C + bx + tx];
    __syncthreads();
#pragma unroll
    for (int i = 0; i < 32; i += 8)
        out[(size_t)(bx + ty + i) * R + by + tx] = f2bf(tile[tx][ty + i]);
}

// ---------------------------------------------------------------------------
// GEMM: C[M][N] = A[M][K] @ B^T (B stored [N][K]) (+ bias)
// SPLIT: 3-product split-bf16 (ah*bh + ah*bl + al*bh) ~ fp32 accuracy
// AF32:  A is f32, converted (and split) on the fly in registers
//        otherwise A is pre-converted bf16 and staged via global_load_lds
// EPIS:  epilogue writes (acc+bias) as split hi/lo bf16; else f32 store
// tile 128x128, BK=32, 4 waves (2x2 of 64x64), mfma_f32_16x16x32_bf16
// ---------------------------------------------------------------------------
template <bool SPLIT, bool AF32, bool EPIS>
__global__ __launch_bounds__(256) void gemm_mfma(
    const void* __restrict__ Aany, const u16* __restrict__ Alo_,
    const u16* __restrict__ Bhi_, const u16* __restrict__ Blo_,
    float* __restrict__ Cf, u16* __restrict__ Chi, u16* __restrict__ Clo,
    const float* __restrict__ bias, int N, int Kd)
{
    constexpr int SA = AF32 ? 48 : 32;   // padded stride only when reg-staged
    __shared__ u16 sAh[128 * SA];
    __shared__ u16 sAl[SPLIT ? 128 * SA : 8];
    __shared__ u16 sBh[128 * 32];
    __shared__ u16 sBl[SPLIT ? 128 * 32 : 8];

    const int t = threadIdx.x;
    const int w = t >> 6;            // wave id 0..3
    const int l = t & 63;            // lane
    const long brow = (long)blockIdx.y * 128;
    const long bcol = (long)blockIdx.x * 128;

    // gload geometry: lane l covers row (i*64 + w*16 + l/4), col8 (l%4)*8
    const int grow = l >> 2;
    const int gcol = (l & 3) * 8;

    // fragment geometry
    const int wr = (w >> 1) * 64;
    const int wc = (w & 1) * 64;
    const int fr = l & 15;
    const int kg = l >> 4;

    f4 acc[4][4];
#pragma unroll
    for (int m = 0; m < 4; m++)
#pragma unroll
        for (int n = 0; n < 4; n++) acc[m][n] = (f4){0.f, 0.f, 0.f, 0.f};

    const int nkt = Kd >> 5;
    for (int kt = 0; kt < nkt; ++kt) {
        const int k0 = kt * 32;

        // ---- stage B (always pre-converted bf16, async direct-to-LDS) ----
#pragma unroll
        for (int i = 0; i < 2; ++i) {
            const long r = bcol + i * 64 + w * 16 + grow;
            const int lb = i * 2048 + w * 512;     // wave-uniform LDS base (elems)
            gl16(Bhi_ + r * Kd + k0 + gcol, sBh + lb);
            if constexpr (SPLIT) gl16(Blo_ + r * Kd + k0 + gcol, sBl + lb);
        }

        // ---- stage A ----
        if constexpr (!AF32) {
            const u16* Ahi = (const u16*)Aany;
#pragma unroll
            for (int i = 0; i < 2; ++i) {
                const long r = brow + i * 64 + w * 16 + grow;
                const int lb = i * 2048 + w * 512;
                gl16(Ahi + r * Kd + k0 + gcol, sAh + lb);
                if constexpr (SPLIT) gl16(Alo_ + r * Kd + k0 + gcol, sAl + lb);
            }
        } else {
            // coalesced f32: 8 lanes x 16B per row, 8 rows per wave per issue
            const float* Af = (const float*)Aany;
            const int ar = w * 8 + (l >> 3);
            const int cF = (l & 7) * 4;
#pragma unroll
            for (int j = 0; j < 4; ++j) {
                const int r = j * 32 + ar;
                const f4 v = *(const f4*)(Af + (brow + r) * (long)Kd + k0 + cF);
                u16 h[4], lw[4];
#pragma unroll
                for (int q = 0; q < 4; ++q) {
                    h[q] = f2bf(v[q]);
                    if constexpr (SPLIT) lw[q] = f2bf(v[q] - bf2f(h[q]));
                }
                *(bf4*)&sAh[r * SA + cF] = *(bf4*)h;
                if constexpr (SPLIT) *(bf4*)&sAl[r * SA + cF] = *(bf4*)lw;
            }
        }
        __syncthreads();

        // ---- fragments + MFMA ----
        bf8 fah[4], fbh[4], fal[4], fbl[4];
#pragma unroll
        for (int m = 0; m < 4; ++m) {
            fah[m] = *(bf8*)&sAh[(wr + m * 16 + fr) * SA + kg * 8];
            fbh[m] = *(bf8*)&sBh[(wc + m * 16 + fr) * 32 + kg * 8];
            if constexpr (SPLIT) {
                fal[m] = *(bf8*)&sAl[(wr + m * 16 + fr) * SA + kg * 8];
                fbl[m] = *(bf8*)&sBl[(wc + m * 16 + fr) * 32 + kg * 8];
            }
        }
#pragma unroll
        for (int m = 0; m < 4; ++m)
#pragma unroll
            for (int n = 0; n < 4; ++n) {
                acc[m][n] = __builtin_amdgcn_mfma_f32_16x16x32_bf16(fah[m], fbh[n], acc[m][n], 0, 0, 0);
                if constexpr (SPLIT) {
                    acc[m][n] = __builtin_amdgcn_mfma_f32_16x16x32_bf16(fah[m], fbl[n], acc[m][n], 0, 0, 0);
                    acc[m][n] = __builtin_amdgcn_mfma_f32_16x16x32_bf16(fal[m], fbh[n], acc[m][n], 0, 0, 0);
                }
            }
        __syncthreads();
    }

    // ---- epilogue: C/D layout col = lane&15, row = (lane>>4)*4 + reg ----
#pragma unroll
    for (int n = 0; n < 4; ++n) {
        const long c = bcol + wc + n * 16 + fr;
        float bv = 0.f;
        if constexpr (EPIS) bv = bias[c];
#pragma unroll
        for (int m = 0; m < 4; ++m) {
            const long r0 = brow + wr + m * 16 + kg * 4;
#pragma unroll
            for (int r = 0; r < 4; ++r) {
                const float v = acc[m][n][r] + bv;
                if constexpr (EPIS) {
                    const u16 h = f2bf(v);
                    Chi[(r0 + r) * (long)N + c] = h;
                    Clo[(r0 + r) * (long)N + c] = f2bf(v - bf2f(h));
                } else {
                    Cf[(r0 + r) * (long)N + c] = v;
                }
            }
        }
    }
}

// ---------------------------------------------------------------------------
// Column softmax over align [N_S rows][N_Kn cols] (softmax along axis 0)
// ---------------------------------------------------------------------------
#define RCHUNK 128

__global__ __launch_bounds__(256) void softmax_partial(
    const float* __restrict__ align, float* __restrict__ pm, float* __restrict__ ps)
{
    const int col = blockIdx.x * 256 + threadIdx.x;
    const int r0 = blockIdx.y * RCHUNK;
    float m = -3.4e38f;
    for (int r = 0; r < RCHUNK; r++)
        m = fmaxf(m, align[(size_t)(r0 + r) * N_Kn + col]);
    float s = 0.f;
    for (int r = 0; r < RCHUNK; r++)
        s += __expf(align[(size_t)(r0 + r) * N_Kn + col] - m);
    pm[(size_t)blockIdx.y * N_Kn + col] = m;
    ps[(size_t)blockIdx.y * N_Kn + col] = s;
}

__global__ __launch_bounds__(256) void softmax_combine(
    const float* __restrict__ pm, const float* __restrict__ ps,
    float* __restrict__ fm, float* __restrict__ fsinv)
{
    const int col = blockIdx.x * 256 + threadIdx.x;
    float m = -3.4e38f;
#pragma unroll
    for (int i = 0; i < 32; i++) m = fmaxf(m, pm[(size_t)i * N_Kn + col]);
    float s = 0.f;
#pragma unroll
    for (int i = 0; i < 32; i++)
        s += ps[(size_t)i * N_Kn + col] * __expf(pm[(size_t)i * N_Kn + col] - m);
    fm[col] = m;
    fsinv[col] = 1.f / s;
}

// normalize in place AND emit a bf16 copy for the final GEMM
__global__ __launch_bounds__(256) void softmax_norm(
    float* __restrict__ align, u16* __restrict__ abf,
    const float* __restrict__ fm, const float* __restrict__ fsinv)
{
    const int col = blockIdx.x * 256 + threadIdx.x;
    const int r0 = blockIdx.y * RCHUNK;
    const float m = fm[col], si = fsinv[col];
    for (int r = 0; r < RCHUNK; r++) {
        const size_t idx = (size_t)(r0 + r) * N_Kn + col;
        const float v = __expf(align[idx] - m) * si;
        align[idx] = v;
        abf[idx] = f2bf(v);
    }
}

// ---------------------------------------------------------------------------
extern "C" void kernel_launch(void* const* d_in, const int* in_sizes, int n_in,
                              void* d_out, int out_size, void* d_ws, size_t ws_size,
                              hipStream_t stream)
{
    const float* sentences = (const float*)d_in[0];  // [4096][1024]
    const float* knowledge = (const float*)d_in[1];  // [8192][3072]
    const float* Ws = (const float*)d_in[2];         // [1024][1024] (in,out)
    const float* bs = (const float*)d_in[3];         // [1024]
    const float* Wk = (const float*)d_in[4];         // [3072][1024]
    const float* bk = (const float*)d_in[5];         // [1024]

    float* out_fused = (float*)d_out;                        // [4096][3072]
    float* out_attn = (float*)d_out + (size_t)N_S * K3;      // [4096][8192]

    // workspace (~114 MB). The first 64 MB (WsT..K_lo) are dead after GEMM4
    // and are reused verbatim as attn_bf16 [4096][8192] (exactly 64 MB).
    char* w = (char*)d_ws;
    u16* attn_bf = (u16*)w;                                  // alias of region below
    u16* WsT_hi = (u16*)w; w += (size_t)HID * SENT * 2;      // [1024][1024]
    u16* WsT_lo = (u16*)w; w += (size_t)HID * SENT * 2;
    u16* WkT_hi = (u16*)w; w += (size_t)HID * K3 * 2;        // [1024][3072]
    u16* WkT_lo = (u16*)w; w += (size_t)HID * K3 * 2;
    u16* S_hi   = (u16*)w; w += (size_t)N_S * HID * 2;       // [4096][1024]
    u16* S_lo   = (u16*)w; w += (size_t)N_S * HID * 2;
    u16* K_hi   = (u16*)w; w += (size_t)N_Kn * HID * 2;      // [8192][1024]
    u16* K_lo   = (u16*)w; w += (size_t)N_Kn * HID * 2;      // (end = 64 MB)
    u16* kT     = (u16*)w; w += (size_t)K3 * N_Kn * 2;       // [3072][8192]
    float* pm   = (float*)w; w += (size_t)32 * N_Kn * 4;
    float* ps   = (float*)w; w += (size_t)32 * N_Kn * 4;
    float* fm   = (float*)w; w += (size_t)N_Kn * 4;
    float* fsv  = (float*)w; w += (size_t)N_Kn * 4;

    // 1. weight transposes (split) + knowledge^T (bf16, hi only)
    transpose_split_f32<<<dim3(HID / 32, SENT / 32), 256, 0, stream>>>(Ws, WsT_hi, WsT_lo, SENT, HID);
    transpose_split_f32<<<dim3(HID / 32, K3 / 32), 256, 0, stream>>>(Wk, WkT_hi, WkT_lo, K3, HID);
    transpose_f32_bf16<<<dim3(K3 / 32, N_Kn / 32), 256, 0, stream>>>(knowledge, kT, N_Kn, K3);

    // 2. S = sentences @ Ws + bs -> split bf16 [4096][1024]
    gemm_mfma<true, true, true><<<dim3(HID / 128, N_S / 128), 256, 0, stream>>>(
        sentences, nullptr, WsT_hi, WsT_lo, nullptr, S_hi, S_lo, bs, HID, SENT);

    // 3. K = knowledge @ Wk + bk -> split bf16 [8192][1024]
    gemm_mfma<true, true, true><<<dim3(HID / 128, N_Kn / 128), 256, 0, stream>>>(
        knowledge, nullptr, WkT_hi, WkT_lo, nullptr, K_hi, K_lo, bk, HID, K3);

    // 4. align = S @ K^T -> f32 into attentions slot (fully gload-staged)
    gemm_mfma<true, false, false><<<dim3(N_Kn / 128, N_S / 128), 256, 0, stream>>>(
        S_hi, S_lo, K_hi, K_lo, out_attn, nullptr, nullptr, nullptr, N_Kn, HID);

    // 5. column softmax (axis 0), in place; also emit bf16 attn into reused ws
    softmax_partial<<<dim3(N_Kn / 256, N_S / RCHUNK), 256, 0, stream>>>(out_attn, pm, ps);
    softmax_combine<<<dim3(N_Kn / 256), 256, 0, stream>>>(pm, ps, fm, fsv);
    softmax_norm<<<dim3(N_Kn / 256, N_S / RCHUNK), 256, 0, stream>>>(out_attn, attn_bf, fm, fsv);

    // 6. fused = attn_bf16 @ kT -> f32 (both operands gload-staged, m97-style)
    gemm_mfma<false, false, false><<<dim3(K3 / 128, N_S / 128), 256, 0, stream>>>(
        attn_bf, nullptr, kT, nullptr, out_fused, nullptr, nullptr, nullptr, K3, N_Kn);
}

// Round 4
// 815.543 us; speedup vs baseline: 1.3172x; 1.0399x over previous
//
#include <hip/hip_runtime.h>
#include <hip/hip_bf16.h>
#include <cstdint>
#include <cstddef>

#define N_S 4096
#define N_Kn 8192
#define HID 1024
#define SENT 1024
#define K3 3072

typedef __attribute__((ext_vector_type(4))) float f4;
typedef __attribute__((ext_vector_type(8))) short bf8;
typedef __attribute__((ext_vector_type(4))) short bf4;
typedef unsigned short u16;

__device__ __forceinline__ u16 f2bf(float x) {
    __hip_bfloat16 h = __float2bfloat16(x);   // HW RNE
    return __builtin_bit_cast(u16, h);
}
__device__ __forceinline__ float bf2f(u16 u) {
    union { unsigned int u; float f; } v; v.u = ((unsigned int)u) << 16;
    return v.f;
}

// async global->LDS, 16 bytes per lane; LDS dest = wave-uniform base + lane*16
__device__ __forceinline__ void gl16(const u16* g, u16* l) {
    __builtin_amdgcn_global_load_lds(
        (const __attribute__((address_space(1))) void*)g,
        (__attribute__((address_space(3))) void*)l, 16, 0, 0);
}

// bijective XCD swizzle (nwg % 8 == 0): each XCD gets a contiguous tile chunk
__device__ __forceinline__ int xcd_swz(int bid, int nwg) {
    const int cpx = nwg >> 3;
    return (bid & 7) * cpx + (bid >> 3);
}

// ---------------------------------------------------------------------------
// Transposes
// ---------------------------------------------------------------------------
__global__ __launch_bounds__(256) void transpose_split_f32(
    const float* __restrict__ in, u16* __restrict__ hi, u16* __restrict__ lo,
    int R, int C)
{
    __shared__ float tile[32][33];
    const int bx = blockIdx.x * 32, by = blockIdx.y * 32;
    const int tx = threadIdx.x & 31, ty = threadIdx.x >> 5;
#pragma unroll
    for (int i = 0; i < 32; i += 8)
        tile[ty + i][tx] = in[(size_t)(by + ty + i) * C + bx + tx];
    __syncthreads();
#pragma unroll
    for (int i = 0; i < 32; i += 8) {
        const float v = tile[tx][ty + i];
        const u16 h = f2bf(v);
        const size_t o = (size_t)(bx + ty + i) * R + by + tx;
        hi[o] = h;
        lo[o] = f2bf(v - bf2f(h));
    }
}

__global__ __launch_bounds__(256) void transpose_f32_bf16(
    const float* __restrict__ in, u16* __restrict__ out, int R, int C)
{
    __shared__ float tile[32][33];
    const int bx = blockIdx.x * 32, by = blockIdx.y * 32;
    const int tx = threadIdx.x & 31, ty = threadIdx.x >> 5;
#pragma unroll
    for (int i = 0; i < 32; i += 8)
        tile[ty + i][tx] = in[(size_t)(by + ty + i) * C + bx + tx];
    __syncthreads();
#pragma unroll
    for (int i = 0; i < 32; i += 8)
        out[(size_t)(bx + ty + i) * R + by + tx] = f2bf(tile[tx][ty + i]);
}

// ---------------------------------------------------------------------------
// gemm_pipe: C[M][N] = A @ B^T, A [M][K] bf16, B [N][K] bf16, f32 out, no bias
// Pipelined: dbuf LDS, per-iter {STAGE(next); compute(cur); vmcnt(0); barrier}
// tile 128x128, BK=32, 4 waves; 1D grid with XCD swizzle.
// ---------------------------------------------------------------------------
__global__ __launch_bounds__(256) void gemm_pipe(
    const u16* __restrict__ A, const u16* __restrict__ B,
    float* __restrict__ C, int N, int Kd, int gx)
{
    __shared__ u16 sA[2][4096];
    __shared__ u16 sB[2][4096];

    const int swz = xcd_swz(blockIdx.x, gridDim.x);
    const int bx = swz % gx, by = swz / gx;

    const int t = threadIdx.x;
    const int w = t >> 6, l = t & 63;
    const long brow = (long)by * 128, bcol = (long)bx * 128;
    const int grow = l >> 2, gcol = (l & 3) * 8;

    const int wr = (w >> 1) * 64, wc = (w & 1) * 64;
    const int fr = l & 15, kg = l >> 4;

    // per-thread staging base pointers (advance by +32 elems per K-tile)
    const u16* gA0 = A + (brow + w * 16 + grow) * (long)Kd + gcol;
    const u16* gA1 = A + (brow + 64 + w * 16 + grow) * (long)Kd + gcol;
    const u16* gB0 = B + (bcol + w * 16 + grow) * (long)Kd + gcol;
    const u16* gB1 = B + (bcol + 64 + w * 16 + grow) * (long)Kd + gcol;
    const int lb0 = w * 512, lb1 = 2048 + w * 512;   // wave-uniform LDS bases

    f4 acc[4][4];
#pragma unroll
    for (int m = 0; m < 4; m++)
#pragma unroll
        for (int n = 0; n < 4; n++) acc[m][n] = (f4){0.f, 0.f, 0.f, 0.f};

    const int nkt = Kd >> 5;

    // prologue: stage tile 0 into buf 0
    gl16(gA0, &sA[0][lb0]); gl16(gA1, &sA[0][lb1]);
    gl16(gB0, &sB[0][lb0]); gl16(gB1, &sB[0][lb1]);
    asm volatile("s_waitcnt vmcnt(0)" ::: "memory");
    __builtin_amdgcn_s_barrier();
    asm volatile("" ::: "memory");

    int cur = 0;
    for (int kt = 0; kt < nkt; ++kt) {
        // stage next tile into the other buffer (async, overlaps compute)
        if (kt + 1 < nkt) {
            const long ko = (long)(kt + 1) * 32;
            const int nx = cur ^ 1;
            gl16(gA0 + ko, &sA[nx][lb0]); gl16(gA1 + ko, &sA[nx][lb1]);
            gl16(gB0 + ko, &sB[nx][lb0]); gl16(gB1 + ko, &sB[nx][lb1]);
        }

        // compute current tile
        bf8 fa[4], fb[4];
#pragma unroll
        for (int m = 0; m < 4; ++m) {
            fa[m] = *(bf8*)&sA[cur][(wr + m * 16 + fr) * 32 + kg * 8];
            fb[m] = *(bf8*)&sB[cur][(wc + m * 16 + fr) * 32 + kg * 8];
        }
#pragma unroll
        for (int m = 0; m < 4; ++m)
#pragma unroll
            for (int n = 0; n < 4; ++n)
                acc[m][n] = __builtin_amdgcn_mfma_f32_16x16x32_bf16(fa[m], fb[n], acc[m][n], 0, 0, 0);

        // next tile's loads must have landed before anyone reads them;
        // barrier also protects buf[cur] from being overwritten next iter.
        asm volatile("s_waitcnt vmcnt(0)" ::: "memory");
        __builtin_amdgcn_s_barrier();
        asm volatile("" ::: "memory");
        cur ^= 1;
    }

    // epilogue: C/D layout col = lane&15, row = (lane>>4)*4 + reg
#pragma unroll
    for (int n = 0; n < 4; ++n) {
        const long c = bcol + wc + n * 16 + fr;
#pragma unroll
        for (int m = 0; m < 4; ++m) {
            const long r0 = brow + wr + m * 16 + kg * 4;
#pragma unroll
            for (int r = 0; r < 4; ++r)
                C[(r0 + r) * (long)N + c] = acc[m][n][r];
        }
    }
}

// ---------------------------------------------------------------------------
// gemm_mfma: C[M][N] = A[M][K] @ B^T (B stored [N][K]) (+ bias)
// SPLIT: 3-product split-bf16; AF32: A f32 converted on the fly;
// EPIS: epilogue writes split hi/lo bf16. 1D grid with XCD swizzle.
// ---------------------------------------------------------------------------
template <bool SPLIT, bool AF32, bool EPIS>
__global__ __launch_bounds__(256) void gemm_mfma(
    const void* __restrict__ Aany, const u16* __restrict__ Alo_,
    const u16* __restrict__ Bhi_, const u16* __restrict__ Blo_,
    float* __restrict__ Cf, u16* __restrict__ Chi, u16* __restrict__ Clo,
    const float* __restrict__ bias, int N, int Kd, int gx)
{
    constexpr int SA = AF32 ? 48 : 32;
    __shared__ u16 sAh[128 * SA];
    __shared__ u16 sAl[SPLIT ? 128 * SA : 8];
    __shared__ u16 sBh[128 * 32];
    __shared__ u16 sBl[SPLIT ? 128 * 32 : 8];

    const int swz = xcd_swz(blockIdx.x, gridDim.x);
    const int bxi = swz % gx, byi = swz / gx;

    const int t = threadIdx.x;
    const int w = t >> 6;
    const int l = t & 63;
    const long brow = (long)byi * 128;
    const long bcol = (long)bxi * 128;

    const int grow = l >> 2;
    const int gcol = (l & 3) * 8;

    const int wr = (w >> 1) * 64;
    const int wc = (w & 1) * 64;
    const int fr = l & 15;
    const int kg = l >> 4;

    f4 acc[4][4];
#pragma unroll
    for (int m = 0; m < 4; m++)
#pragma unroll
        for (int n = 0; n < 4; n++) acc[m][n] = (f4){0.f, 0.f, 0.f, 0.f};

    const int nkt = Kd >> 5;
    for (int kt = 0; kt < nkt; ++kt) {
        const int k0 = kt * 32;

#pragma unroll
        for (int i = 0; i < 2; ++i) {
            const long r = bcol + i * 64 + w * 16 + grow;
            const int lb = i * 2048 + w * 512;
            gl16(Bhi_ + r * Kd + k0 + gcol, sBh + lb);
            if constexpr (SPLIT) gl16(Blo_ + r * Kd + k0 + gcol, sBl + lb);
        }

        if constexpr (!AF32) {
            const u16* Ahi = (const u16*)Aany;
#pragma unroll
            for (int i = 0; i < 2; ++i) {
                const long r = brow + i * 64 + w * 16 + grow;
                const int lb = i * 2048 + w * 512;
                gl16(Ahi + r * Kd + k0 + gcol, sAh + lb);
                if constexpr (SPLIT) gl16(Alo_ + r * Kd + k0 + gcol, sAl + lb);
            }
        } else {
            const float* Af = (const float*)Aany;
            const int ar = w * 8 + (l >> 3);
            const int cF = (l & 7) * 4;
#pragma unroll
            for (int j = 0; j < 4; ++j) {
                const int r = j * 32 + ar;
                const f4 v = *(const f4*)(Af + (brow + r) * (long)Kd + k0 + cF);
                u16 h[4], lw[4];
#pragma unroll
                for (int q = 0; q < 4; ++q) {
                    h[q] = f2bf(v[q]);
                    if constexpr (SPLIT) lw[q] = f2bf(v[q] - bf2f(h[q]));
                }
                *(bf4*)&sAh[r * SA + cF] = *(bf4*)h;
                if constexpr (SPLIT) *(bf4*)&sAl[r * SA + cF] = *(bf4*)lw;
            }
        }
        __syncthreads();

        bf8 fah[4], fbh[4], fal[4], fbl[4];
#pragma unroll
        for (int m = 0; m < 4; ++m) {
            fah[m] = *(bf8*)&sAh[(wr + m * 16 + fr) * SA + kg * 8];
            fbh[m] = *(bf8*)&sBh[(wc + m * 16 + fr) * 32 + kg * 8];
            if constexpr (SPLIT) {
                fal[m] = *(bf8*)&sAl[(wr + m * 16 + fr) * SA + kg * 8];
                fbl[m] = *(bf8*)&sBl[(wc + m * 16 + fr) * 32 + kg * 8];
            }
        }
#pragma unroll
        for (int m = 0; m < 4; ++m)
#pragma unroll
            for (int n = 0; n < 4; ++n) {
                acc[m][n] = __builtin_amdgcn_mfma_f32_16x16x32_bf16(fah[m], fbh[n], acc[m][n], 0, 0, 0);
                if constexpr (SPLIT) {
                    acc[m][n] = __builtin_amdgcn_mfma_f32_16x16x32_bf16(fah[m], fbl[n], acc[m][n], 0, 0, 0);
                    acc[m][n] = __builtin_amdgcn_mfma_f32_16x16x32_bf16(fal[m], fbh[n], acc[m][n], 0, 0, 0);
                }
            }
        __syncthreads();
    }

#pragma unroll
    for (int n = 0; n < 4; ++n) {
        const long c = bcol + wc + n * 16 + fr;
        float bv = 0.f;
        if constexpr (EPIS) bv = bias[c];
#pragma unroll
        for (int m = 0; m < 4; ++m) {
            const long r0 = brow + wr + m * 16 + kg * 4;
#pragma unroll
            for (int r = 0; r < 4; ++r) {
                const float v = acc[m][n][r] + bv;
                if constexpr (EPIS) {
                    const u16 h = f2bf(v);
                    Chi[(r0 + r) * (long)N + c] = h;
                    Clo[(r0 + r) * (long)N + c] = f2bf(v - bf2f(h));
                } else {
                    Cf[(r0 + r) * (long)N + c] = v;
                }
            }
        }
    }
}

// ---------------------------------------------------------------------------
// Column softmax over align [N_S rows][N_Kn cols] (softmax along axis 0)
// ---------------------------------------------------------------------------
#define RCHUNK 128

__global__ __launch_bounds__(256) void softmax_partial(
    const float* __restrict__ align, float* __restrict__ pm, float* __restrict__ ps)
{
    const int col = blockIdx.x * 256 + threadIdx.x;
    const int r0 = blockIdx.y * RCHUNK;
    float m = -3.4e38f;
    for (int r = 0; r < RCHUNK; r++)
        m = fmaxf(m, align[(size_t)(r0 + r) * N_Kn + col]);
    float s = 0.f;
    for (int r = 0; r < RCHUNK; r++)
        s += __expf(align[(size_t)(r0 + r) * N_Kn + col] - m);
    pm[(size_t)blockIdx.y * N_Kn + col] = m;
    ps[(size_t)blockIdx.y * N_Kn + col] = s;
}

__global__ __launch_bounds__(256) void softmax_combine(
    const float* __restrict__ pm, const float* __restrict__ ps,
    float* __restrict__ fm, float* __restrict__ fsinv)
{
    const int col = blockIdx.x * 256 + threadIdx.x;
    float m = -3.4e38f;
#pragma unroll
    for (int i = 0; i < 32; i++) m = fmaxf(m, pm[(size_t)i * N_Kn + col]);
    float s = 0.f;
#pragma unroll
    for (int i = 0; i < 32; i++)
        s += ps[(size_t)i * N_Kn + col] * __expf(pm[(size_t)i * N_Kn + col] - m);
    fm[col] = m;
    fsinv[col] = 1.f / s;
}

__global__ __launch_bounds__(256) void softmax_norm(
    float* __restrict__ align, u16* __restrict__ abf,
    const float* __restrict__ fm, const float* __restrict__ fsinv)
{
    const int col = blockIdx.x * 256 + threadIdx.x;
    const int r0 = blockIdx.y * RCHUNK;
    const float m = fm[col], si = fsinv[col];
    for (int r = 0; r < RCHUNK; r++) {
        const size_t idx = (size_t)(r0 + r) * N_Kn + col;
        const float v = __expf(align[idx] - m) * si;
        align[idx] = v;
        abf[idx] = f2bf(v);
    }
}

// ---------------------------------------------------------------------------
extern "C" void kernel_launch(void* const* d_in, const int* in_sizes, int n_in,
                              void* d_out, int out_size, void* d_ws, size_t ws_size,
                              hipStream_t stream)
{
    const float* sentences = (const float*)d_in[0];  // [4096][1024]
    const float* knowledge = (const float*)d_in[1];  // [8192][3072]
    const float* Ws = (const float*)d_in[2];         // [1024][1024]
    const float* bs = (const float*)d_in[3];         // [1024]
    const float* Wk = (const float*)d_in[4];         // [3072][1024]
    const float* bk = (const float*)d_in[5];         // [1024]

    float* out_fused = (float*)d_out;                        // [4096][3072]
    float* out_attn = (float*)d_out + (size_t)N_S * K3;      // [4096][8192]

    // workspace (~114 MB); first 64 MB reused as attn_bf16 after GEMM4
    char* w = (char*)d_ws;
    u16* attn_bf = (u16*)w;
    u16* WsT_hi = (u16*)w; w += (size_t)HID * SENT * 2;
    u16* WsT_lo = (u16*)w; w += (size_t)HID * SENT * 2;
    u16* WkT_hi = (u16*)w; w += (size_t)HID * K3 * 2;
    u16* WkT_lo = (u16*)w; w += (size_t)HID * K3 * 2;
    u16* S_hi   = (u16*)w; w += (size_t)N_S * HID * 2;
    u16* S_lo   = (u16*)w; w += (size_t)N_S * HID * 2;
    u16* K_hi   = (u16*)w; w += (size_t)N_Kn * HID * 2;
    u16* K_lo   = (u16*)w; w += (size_t)N_Kn * HID * 2;      // end = 64 MB
    u16* kT     = (u16*)w; w += (size_t)K3 * N_Kn * 2;
    float* pm   = (float*)w; w += (size_t)32 * N_Kn * 4;
    float* ps   = (float*)w; w += (size_t)32 * N_Kn * 4;
    float* fm   = (float*)w; w += (size_t)N_Kn * 4;
    float* fsv  = (float*)w; w += (size_t)N_Kn * 4;

    // 1. weight transposes (split) + knowledge^T (bf16)
    transpose_split_f32<<<dim3(HID / 32, SENT / 32), 256, 0, stream>>>(Ws, WsT_hi, WsT_lo, SENT, HID);
    transpose_split_f32<<<dim3(HID / 32, K3 / 32), 256, 0, stream>>>(Wk, WkT_hi, WkT_lo, K3, HID);
    transpose_f32_bf16<<<dim3(K3 / 32, N_Kn / 32), 256, 0, stream>>>(knowledge, kT, N_Kn, K3);

    // 2. S = sentences @ Ws + bs -> split bf16
    gemm_mfma<true, true, true><<<(HID / 128) * (N_S / 128), 256, 0, stream>>>(
        sentences, nullptr, WsT_hi, WsT_lo, nullptr, S_hi, S_lo, bs, HID, SENT, HID / 128);

    // 3. K = knowledge @ Wk + bk -> split bf16
    gemm_mfma<true, true, true><<<(HID / 128) * (N_Kn / 128), 256, 0, stream>>>(
        knowledge, nullptr, WkT_hi, WkT_lo, nullptr, K_hi, K_lo, bk, HID, K3, HID / 128);

    // 4. align = S @ K^T -> f32 into attentions slot
    gemm_mfma<true, false, false><<<(N_Kn / 128) * (N_S / 128), 256, 0, stream>>>(
        S_hi, S_lo, K_hi, K_lo, out_attn, nullptr, nullptr, nullptr, N_Kn, HID, N_Kn / 128);

    // 5. column softmax (axis 0), in place; emit bf16 attn into reused ws
    softmax_partial<<<dim3(N_Kn / 256, N_S / RCHUNK), 256, 0, stream>>>(out_attn, pm, ps);
    softmax_combine<<<dim3(N_Kn / 256), 256, 0, stream>>>(pm, ps, fm, fsv);
    softmax_norm<<<dim3(N_Kn / 256, N_S / RCHUNK), 256, 0, stream>>>(out_attn, attn_bf, fm, fsv);

    // 6. fused = attn_bf16 @ kT -> f32 (pipelined)
    gemm_pipe<<<(K3 / 128) * (N_S / 128), 256, 0, stream>>>(
        attn_bf, kT, out_fused, K3, N_Kn, K3 / 128);
}

// Round 5
// 812.278 us; speedup vs baseline: 1.3225x; 1.0040x over previous
//
#include <hip/hip_runtime.h>
#include <hip/hip_bf16.h>
#include <cstdint>
#include <cstddef>

#define N_S 4096
#define N_Kn 8192
#define HID 1024
#define SENT 1024
#define K3 3072

typedef __attribute__((ext_vector_type(4))) float f4;
typedef __attribute__((ext_vector_type(8))) short bf8;
typedef __attribute__((ext_vector_type(4))) short bf4;
typedef unsigned short u16;

__device__ __forceinline__ u16 f2bf(float x) {
    __hip_bfloat16 h = __float2bfloat16(x);   // HW RNE
    return __builtin_bit_cast(u16, h);
}
__device__ __forceinline__ float bf2f(u16 u) {
    union { unsigned int u; float f; } v; v.u = ((unsigned int)u) << 16;
    return v.f;
}

// async global->LDS, 16 bytes per lane; LDS dest = wave-uniform base + lane*16
__device__ __forceinline__ void gl16(const u16* g, u16* l) {
    __builtin_amdgcn_global_load_lds(
        (const __attribute__((address_space(1))) void*)g,
        (__attribute__((address_space(3))) void*)l, 16, 0, 0);
}

// bijective XCD swizzle (nwg % 8 == 0)
__device__ __forceinline__ int xcd_swz(int bid, int nwg) {
    const int cpx = nwg >> 3;
    return (bid & 7) * cpx + (bid >> 3);
}

// LDS chunk swizzle for [rows][32]-bf16 tiles staged via gl16 (rule #21):
// LDS write stays linear; the per-lane GLOBAL source chunk is permuted by
// c' = c ^ ((row>>1)&3); reads apply the same XOR. Rows then spread across
// all 8 bank-quads -> 2-way residual conflict (free, m136).
// staging: lane l covers row (l>>2), source chunk (l&3) ^ ((l>>3)&3)
// read:    row r, logical chunk kg -> LDS chunk kg ^ ((r>>1)&3)

// ---------------------------------------------------------------------------
// Transposes
// ---------------------------------------------------------------------------
__global__ __launch_bounds__(256) void transpose_split_f32(
    const float* __restrict__ in, u16* __restrict__ hi, u16* __restrict__ lo,
    int R, int C)
{
    __shared__ float tile[32][33];
    const int bx = blockIdx.x * 32, by = blockIdx.y * 32;
    const int tx = threadIdx.x & 31, ty = threadIdx.x >> 5;
#pragma unroll
    for (int i = 0; i < 32; i += 8)
        tile[ty + i][tx] = in[(size_t)(by + ty + i) * C + bx + tx];
    __syncthreads();
#pragma unroll
    for (int i = 0; i < 32; i += 8) {
        const float v = tile[tx][ty + i];
        const u16 h = f2bf(v);
        const size_t o = (size_t)(bx + ty + i) * R + by + tx;
        hi[o] = h;
        lo[o] = f2bf(v - bf2f(h));
    }
}

__global__ __launch_bounds__(256) void transpose_f32_bf16(
    const float* __restrict__ in, u16* __restrict__ out, int R, int C)
{
    __shared__ float tile[32][33];
    const int bx = blockIdx.x * 32, by = blockIdx.y * 32;
    const int tx = threadIdx.x & 31, ty = threadIdx.x >> 5;
#pragma unroll
    for (int i = 0; i < 32; i += 8)
        tile[ty + i][tx] = in[(size_t)(by + ty + i) * C + bx + tx];
    __syncthreads();
#pragma unroll
    for (int i = 0; i < 32; i += 8)
        out[(size_t)(bx + ty + i) * R + by + tx] = f2bf(tile[tx][ty + i]);
}

// ---------------------------------------------------------------------------
// gemm_pipe: C[M][N] = A @ B^T, A [M][K] bf16, B [N][K] bf16, f32 out
// dbuf LDS pipeline, swizzled staging/reads, XCD-swizzled 1D grid.
// ---------------------------------------------------------------------------
__global__ __launch_bounds__(256) void gemm_pipe(
    const u16* __restrict__ A, const u16* __restrict__ B,
    float* __restrict__ C, int N, int Kd, int gx)
{
    __shared__ u16 sA[2][4096];
    __shared__ u16 sB[2][4096];

    const int swz = xcd_swz(blockIdx.x, gridDim.x);
    const int bx = swz % gx, by = swz / gx;

    const int t = threadIdx.x;
    const int w = t >> 6, l = t & 63;
    const long brow = (long)by * 128, bcol = (long)bx * 128;
    const int grow = l >> 2;
    const int gcol = ((l & 3) ^ ((l >> 3) & 3)) * 8;   // pre-swizzled source chunk

    const int wr = (w >> 1) * 64, wc = (w & 1) * 64;
    const int fr = l & 15, kg = l >> 4;
    const int kq = (kg ^ ((fr >> 1) & 3)) * 8;         // swizzled read chunk

    const u16* gA0 = A + (brow + w * 16 + grow) * (long)Kd + gcol;
    const u16* gA1 = A + (brow + 64 + w * 16 + grow) * (long)Kd + gcol;
    const u16* gB0 = B + (bcol + w * 16 + grow) * (long)Kd + gcol;
    const u16* gB1 = B + (bcol + 64 + w * 16 + grow) * (long)Kd + gcol;
    const int lb0 = w * 512, lb1 = 2048 + w * 512;

    f4 acc[4][4];
#pragma unroll
    for (int m = 0; m < 4; m++)
#pragma unroll
        for (int n = 0; n < 4; n++) acc[m][n] = (f4){0.f, 0.f, 0.f, 0.f};

    const int nkt = Kd >> 5;

    gl16(gA0, &sA[0][lb0]); gl16(gA1, &sA[0][lb1]);
    gl16(gB0, &sB[0][lb0]); gl16(gB1, &sB[0][lb1]);
    asm volatile("s_waitcnt vmcnt(0)" ::: "memory");
    __builtin_amdgcn_s_barrier();
    asm volatile("" ::: "memory");

    int cur = 0;
    for (int kt = 0; kt < nkt; ++kt) {
        if (kt + 1 < nkt) {
            const long ko = (long)(kt + 1) * 32;
            const int nx = cur ^ 1;
            gl16(gA0 + ko, &sA[nx][lb0]); gl16(gA1 + ko, &sA[nx][lb1]);
            gl16(gB0 + ko, &sB[nx][lb0]); gl16(gB1 + ko, &sB[nx][lb1]);
        }

        bf8 fa[4], fb[4];
#pragma unroll
        for (int m = 0; m < 4; ++m) {
            fa[m] = *(bf8*)&sA[cur][(wr + m * 16 + fr) * 32 + kq];
            fb[m] = *(bf8*)&sB[cur][(wc + m * 16 + fr) * 32 + kq];
        }
#pragma unroll
        for (int m = 0; m < 4; ++m)
#pragma unroll
            for (int n = 0; n < 4; ++n)
                acc[m][n] = __builtin_amdgcn_mfma_f32_16x16x32_bf16(fa[m], fb[n], acc[m][n], 0, 0, 0);

        asm volatile("s_waitcnt vmcnt(0)" ::: "memory");
        __builtin_amdgcn_s_barrier();
        asm volatile("" ::: "memory");
        cur ^= 1;
    }

#pragma unroll
    for (int n = 0; n < 4; ++n) {
        const long c = bcol + wc + n * 16 + fr;
#pragma unroll
        for (int m = 0; m < 4; ++m) {
            const long r0 = brow + wr + m * 16 + kg * 4;
#pragma unroll
            for (int r = 0; r < 4; ++r)
                C[(r0 + r) * (long)N + c] = acc[m][n][r];
        }
    }
}

// ---------------------------------------------------------------------------
// gemm_mfma: C[M][N] = A[M][K] @ B^T (+ bias); SPLIT/AF32/EPIS as before.
// gl16-staged operands use the chunk swizzle; AF32 A path keeps 48-pad.
// ---------------------------------------------------------------------------
template <bool SPLIT, bool AF32, bool EPIS>
__global__ __launch_bounds__(256) void gemm_mfma(
    const void* __restrict__ Aany, const u16* __restrict__ Alo_,
    const u16* __restrict__ Bhi_, const u16* __restrict__ Blo_,
    float* __restrict__ Cf, u16* __restrict__ Chi, u16* __restrict__ Clo,
    const float* __restrict__ bias, int N, int Kd, int gx)
{
    constexpr int SA = AF32 ? 48 : 32;
    __shared__ u16 sAh[128 * SA];
    __shared__ u16 sAl[SPLIT ? 128 * SA : 8];
    __shared__ u16 sBh[128 * 32];
    __shared__ u16 sBl[SPLIT ? 128 * 32 : 8];

    const int swz = xcd_swz(blockIdx.x, gridDim.x);
    const int bxi = swz % gx, byi = swz / gx;

    const int t = threadIdx.x;
    const int w = t >> 6;
    const int l = t & 63;
    const long brow = (long)byi * 128;
    const long bcol = (long)bxi * 128;

    const int grow = l >> 2;
    const int gcol = ((l & 3) ^ ((l >> 3) & 3)) * 8;   // pre-swizzled source chunk

    const int wr = (w >> 1) * 64;
    const int wc = (w & 1) * 64;
    const int fr = l & 15;
    const int kg = l >> 4;
    const int kq = (kg ^ ((fr >> 1) & 3)) * 8;         // swizzled read chunk

    f4 acc[4][4];
#pragma unroll
    for (int m = 0; m < 4; m++)
#pragma unroll
        for (int n = 0; n < 4; n++) acc[m][n] = (f4){0.f, 0.f, 0.f, 0.f};

    const int nkt = Kd >> 5;
    for (int kt = 0; kt < nkt; ++kt) {
        const int k0 = kt * 32;

#pragma unroll
        for (int i = 0; i < 2; ++i) {
            const long r = bcol + i * 64 + w * 16 + grow;
            const int lb = i * 2048 + w * 512;
            gl16(Bhi_ + r * Kd + k0 + gcol, sBh + lb);
            if constexpr (SPLIT) gl16(Blo_ + r * Kd + k0 + gcol, sBl + lb);
        }

        if constexpr (!AF32) {
            const u16* Ahi = (const u16*)Aany;
#pragma unroll
            for (int i = 0; i < 2; ++i) {
                const long r = brow + i * 64 + w * 16 + grow;
                const int lb = i * 2048 + w * 512;
                gl16(Ahi + r * Kd + k0 + gcol, sAh + lb);
                if constexpr (SPLIT) gl16(Alo_ + r * Kd + k0 + gcol, sAl + lb);
            }
        } else {
            const float* Af = (const float*)Aany;
            const int ar = w * 8 + (l >> 3);
            const int cF = (l & 7) * 4;
#pragma unroll
            for (int j = 0; j < 4; ++j) {
                const int r = j * 32 + ar;
                const f4 v = *(const f4*)(Af + (brow + r) * (long)Kd + k0 + cF);
                u16 h[4], lw[4];
#pragma unroll
                for (int q = 0; q < 4; ++q) {
                    h[q] = f2bf(v[q]);
                    if constexpr (SPLIT) lw[q] = f2bf(v[q] - bf2f(h[q]));
                }
                *(bf4*)&sAh[r * SA + cF] = *(bf4*)h;
                if constexpr (SPLIT) *(bf4*)&sAl[r * SA + cF] = *(bf4*)lw;
            }
        }
        __syncthreads();

        bf8 fah[4], fbh[4], fal[4], fbl[4];
#pragma unroll
        for (int m = 0; m < 4; ++m) {
            // A: swizzled read iff gl16-staged; AF32 path is padded-linear
            if constexpr (AF32) {
                fah[m] = *(bf8*)&sAh[(wr + m * 16 + fr) * SA + kg * 8];
                if constexpr (SPLIT) fal[m] = *(bf8*)&sAl[(wr + m * 16 + fr) * SA + kg * 8];
            } else {
                fah[m] = *(bf8*)&sAh[(wr + m * 16 + fr) * 32 + kq];
                if constexpr (SPLIT) fal[m] = *(bf8*)&sAl[(wr + m * 16 + fr) * 32 + kq];
            }
            fbh[m] = *(bf8*)&sBh[(wc + m * 16 + fr) * 32 + kq];
            if constexpr (SPLIT) fbl[m] = *(bf8*)&sBl[(wc + m * 16 + fr) * 32 + kq];
        }
#pragma unroll
        for (int m = 0; m < 4; ++m)
#pragma unroll
            for (int n = 0; n < 4; ++n) {
                acc[m][n] = __builtin_amdgcn_mfma_f32_16x16x32_bf16(fah[m], fbh[n], acc[m][n], 0, 0, 0);
                if constexpr (SPLIT) {
                    acc[m][n] = __builtin_amdgcn_mfma_f32_16x16x32_bf16(fah[m], fbl[n], acc[m][n], 0, 0, 0);
                    acc[m][n] = __builtin_amdgcn_mfma_f32_16x16x32_bf16(fal[m], fbh[n], acc[m][n], 0, 0, 0);
                }
            }
        __syncthreads();
    }

#pragma unroll
    for (int n = 0; n < 4; ++n) {
        const long c = bcol + wc + n * 16 + fr;
        float bv = 0.f;
        if constexpr (EPIS) bv = bias[c];
#pragma unroll
        for (int m = 0; m < 4; ++m) {
            const long r0 = brow + wr + m * 16 + kg * 4;
#pragma unroll
            for (int r = 0; r < 4; ++r) {
                const float v = acc[m][n][r] + bv;
                if constexpr (EPIS) {
                    const u16 h = f2bf(v);
                    Chi[(r0 + r) * (long)N + c] = h;
                    Clo[(r0 + r) * (long)N + c] = f2bf(v - bf2f(h));
                } else {
                    Cf[(r0 + r) * (long)N + c] = v;
                }
            }
        }
    }
}

// ---------------------------------------------------------------------------
// Column softmax over align [N_S rows][N_Kn cols] (softmax along axis 0)
// ---------------------------------------------------------------------------
#define RCHUNK 128

__global__ __launch_bounds__(256) void softmax_partial(
    const float* __restrict__ align, float* __restrict__ pm, float* __restrict__ ps)
{
    const int col = blockIdx.x * 256 + threadIdx.x;
    const int r0 = blockIdx.y * RCHUNK;
    float m = -3.4e38f;
    for (int r = 0; r < RCHUNK; r++)
        m = fmaxf(m, align[(size_t)(r0 + r) * N_Kn + col]);
    float s = 0.f;
    for (int r = 0; r < RCHUNK; r++)
        s += __expf(align[(size_t)(r0 + r) * N_Kn + col] - m);
    pm[(size_t)blockIdx.y * N_Kn + col] = m;
    ps[(size_t)blockIdx.y * N_Kn + col] = s;
}

__global__ __launch_bounds__(256) void softmax_combine(
    const float* __restrict__ pm, const float* __restrict__ ps,
    float* __restrict__ fm, float* __restrict__ fsinv)
{
    const int col = blockIdx.x * 256 + threadIdx.x;
    float m = -3.4e38f;
#pragma unroll
    for (int i = 0; i < 32; i++) m = fmaxf(m, pm[(size_t)i * N_Kn + col]);
    float s = 0.f;
#pragma unroll
    for (int i = 0; i < 32; i++)
        s += ps[(size_t)i * N_Kn + col] * __expf(pm[(size_t)i * N_Kn + col] - m);
    fm[col] = m;
    fsinv[col] = 1.f / s;
}

__global__ __launch_bounds__(256) void softmax_norm(
    float* __restrict__ align, u16* __restrict__ abf,
    const float* __restrict__ fm, const float* __restrict__ fsinv)
{
    const int col = blockIdx.x * 256 + threadIdx.x;
    const int r0 = blockIdx.y * RCHUNK;
    const float m = fm[col], si = fsinv[col];
    for (int r = 0; r < RCHUNK; r++) {
        const size_t idx = (size_t)(r0 + r) * N_Kn + col;
        const float v = __expf(align[idx] - m) * si;
        align[idx] = v;
        abf[idx] = f2bf(v);
    }
}

// ---------------------------------------------------------------------------
extern "C" void kernel_launch(void* const* d_in, const int* in_sizes, int n_in,
                              void* d_out, int out_size, void* d_ws, size_t ws_size,
                              hipStream_t stream)
{
    const float* sentences = (const float*)d_in[0];  // [4096][1024]
    const float* knowledge = (const float*)d_in[1];  // [8192][3072]
    const float* Ws = (const float*)d_in[2];         // [1024][1024]
    const float* bs = (const float*)d_in[3];         // [1024]
    const float* Wk = (const float*)d_in[4];         // [3072][1024]
    const float* bk = (const float*)d_in[5];         // [1024]

    float* out_fused = (float*)d_out;                        // [4096][3072]
    float* out_attn = (float*)d_out + (size_t)N_S * K3;      // [4096][8192]

    // workspace (~114 MB); first 64 MB reused as attn_bf16 after GEMM4
    char* w = (char*)d_ws;
    u16* attn_bf = (u16*)w;
    u16* WsT_hi = (u16*)w; w += (size_t)HID * SENT * 2;
    u16* WsT_lo = (u16*)w; w += (size_t)HID * SENT * 2;
    u16* WkT_hi = (u16*)w; w += (size_t)HID * K3 * 2;
    u16* WkT_lo = (u16*)w; w += (size_t)HID * K3 * 2;
    u16* S_hi   = (u16*)w; w += (size_t)N_S * HID * 2;
    u16* S_lo   = (u16*)w; w += (size_t)N_S * HID * 2;
    u16* K_hi   = (u16*)w; w += (size_t)N_Kn * HID * 2;
    u16* K_lo   = (u16*)w; w += (size_t)N_Kn * HID * 2;      // end = 64 MB
    u16* kT     = (u16*)w; w += (size_t)K3 * N_Kn * 2;
    float* pm   = (float*)w; w += (size_t)32 * N_Kn * 4;
    float* ps   = (float*)w; w += (size_t)32 * N_Kn * 4;
    float* fm   = (float*)w; w += (size_t)N_Kn * 4;
    float* fsv  = (float*)w; w += (size_t)N_Kn * 4;

    // 1. weight transposes (split) + knowledge^T (bf16)
    transpose_split_f32<<<dim3(HID / 32, SENT / 32), 256, 0, stream>>>(Ws, WsT_hi, WsT_lo, SENT, HID);
    transpose_split_f32<<<dim3(HID / 32, K3 / 32), 256, 0, stream>>>(Wk, WkT_hi, WkT_lo, K3, HID);
    transpose_f32_bf16<<<dim3(K3 / 32, N_Kn / 32), 256, 0, stream>>>(knowledge, kT, N_Kn, K3);

    // 2. S = sentences @ Ws + bs -> split bf16
    gemm_mfma<true, true, true><<<(HID / 128) * (N_S / 128), 256, 0, stream>>>(
        sentences, nullptr, WsT_hi, WsT_lo, nullptr, S_hi, S_lo, bs, HID, SENT, HID / 128);

    // 3. K = knowledge @ Wk + bk -> split bf16
    gemm_mfma<true, true, true><<<(HID / 128) * (N_Kn / 128), 256, 0, stream>>>(
        knowledge, nullptr, WkT_hi, WkT_lo, nullptr, K_hi, K_lo, bk, HID, K3, HID / 128);

    // 4. align = S @ K^T -> f32 into attentions slot
    gemm_mfma<true, false, false><<<(N_Kn / 128) * (N_S / 128), 256, 0, stream>>>(
        S_hi, S_lo, K_hi, K_lo, out_attn, nullptr, nullptr, nullptr, N_Kn, HID, N_Kn / 128);

    // 5. column softmax (axis 0), in place; emit bf16 attn into reused ws
    softmax_partial<<<dim3(N_Kn / 256, N_S / RCHUNK), 256, 0, stream>>>(out_attn, pm, ps);
    softmax_combine<<<dim3(N_Kn / 256), 256, 0, stream>>>(pm, ps, fm, fsv);
    softmax_norm<<<dim3(N_Kn / 256, N_S / RCHUNK), 256, 0, stream>>>(out_attn, attn_bf, fm, fsv);

    // 6. fused = attn_bf16 @ kT -> f32 (pipelined, swizzled)
    gemm_pipe<<<(K3 / 128) * (N_S / 128), 256, 0, stream>>>(
        attn_bf, kT, out_fused, K3, N_Kn, K3 / 128);
}